// Round 4
// baseline (301.354 us; speedup 1.0000x reference)
//
#include <hip/hip_runtime.h>

#define L_DIM 4096
#define C_DIM 256
#define B_DIM 4
#define NH 8
#define DK 32

// Folds softmax 1/sqrt(DK) AND log2(e) into Q at projection time, so the
// attention kernel uses a single v_exp_f32 (exp2) per score.
#define QSCALE 0.25507694f   // (1/sqrt(32)) * log2(e)

typedef __bf16 bf16x8 __attribute__((ext_vector_type(8)));
typedef float  f32x4  __attribute__((ext_vector_type(4)));
typedef float  f32x16 __attribute__((ext_vector_type(16)));

// pack two f32 -> packed bf16 pair (round-to-nearest via +0x8000, then byte-perm)
// safe here: inputs are exp() outputs (positive, finite, not near overflow)
static __device__ __forceinline__ unsigned pk_bf16(float lo, float hi) {
    unsigned a = __builtin_bit_cast(unsigned, lo) + 0x8000u;
    unsigned b = __builtin_bit_cast(unsigned, hi) + 0x8000u;
    return __builtin_amdgcn_perm(b, a, 0x07060302u);   // {b[31:16], a[31:16]}
}

// ---------------------------------------------------------------------------
// Kernel 1: Q/K/V projections as register-blocked fp32 GEMM (unchanged).
// ---------------------------------------------------------------------------
__global__ __launch_bounds__(256) void proj_qkv_kernel(
    const float* __restrict__ x, const float* __restrict__ Wq,
    const float* __restrict__ Wk, const float* __restrict__ Wv,
    __bf16* __restrict__ Qb, __bf16* __restrict__ Kb, __bf16* __restrict__ Vb)
{
    const int t   = threadIdx.x;
    const int col = t & 15;
    const int row = t >> 4;
    const int l0  = blockIdx.x * 128;
    const int ob  = blockIdx.y & 1;
    const int p   = blockIdx.y >> 1;
    const int b   = blockIdx.z;
    const float* W = (p == 0) ? Wq : ((p == 1) ? Wk : Wv);

    __shared__ __attribute__((aligned(16))) float Ws[32][132];
    __shared__ __attribute__((aligned(16))) float Xs[32][132];

    const int xc = t >> 3, xl = (t & 7) * 16;
    const int wo = t >> 1, wc = (t & 1) * 16;
    const float* xg = x + (size_t)b * C_DIM * L_DIM + (size_t)xc * L_DIM + l0 + xl;
    const float* wg = W + (size_t)(ob * 128 + wo) * C_DIM + wc;

    float acc[8][8];
    #pragma unroll
    for (int i = 0; i < 8; ++i)
        #pragma unroll
        for (int j = 0; j < 8; ++j) acc[i][j] = 0.f;

    f32x4 xr[4], wr[4];
    #pragma unroll
    for (int k = 0; k < 4; ++k) {
        xr[k] = *(const f32x4*)(xg + k * 4);
        wr[k] = *(const f32x4*)(wg + k * 4);
    }

    for (int ch = 0; ch < 8; ++ch) {
        __syncthreads();
        #pragma unroll
        for (int k = 0; k < 4; ++k) {
            *(f32x4*)&Xs[xc][xl + k * 4] = xr[k];
            #pragma unroll
            for (int u = 0; u < 4; ++u)
                Ws[wc + k * 4 + u][wo] = wr[k][u];
        }
        if (ch < 7) {
            #pragma unroll
            for (int k = 0; k < 4; ++k) {
                xr[k] = *(const f32x4*)(xg + (size_t)(ch + 1) * 32 * L_DIM + k * 4);
                wr[k] = *(const f32x4*)(wg + (ch + 1) * 32 + k * 4);
            }
        }
        __syncthreads();

        #pragma unroll 4
        for (int c = 0; c < 32; ++c) {
            const f32x4 w0 = *(const f32x4*)&Ws[c][row * 8];
            const f32x4 w1 = *(const f32x4*)&Ws[c][row * 8 + 4];
            const f32x4 x0 = *(const f32x4*)&Xs[c][col * 8];
            const f32x4 x1 = *(const f32x4*)&Xs[c][col * 8 + 4];
            #pragma unroll
            for (int i = 0; i < 4; ++i)
                #pragma unroll
                for (int j = 0; j < 4; ++j) {
                    acc[i][j]         += w0[i] * x0[j];
                    acc[i][j + 4]     += w0[i] * x1[j];
                    acc[i + 4][j]     += w1[i] * x0[j];
                    acc[i + 4][j + 4] += w1[i] * x1[j];
                }
        }
    }

    const int h      = ob * 4 + (row >> 2);
    const int dkbase = (row & 3) * 8;

    if (p < 2) {
        __bf16* out = (p == 0) ? Qb : Kb;
        const float sc = (p == 0) ? QSCALE : 1.0f;
        #pragma unroll
        for (int j = 0; j < 8; ++j) {
            const int l = l0 + col * 8 + j;
            bf16x8 pk;
            #pragma unroll
            for (int i = 0; i < 8; ++i) pk[i] = (__bf16)(acc[i][j] * sc);
            *(bf16x8*)&out[((size_t)(b * NH + h) * L_DIM + l) * DK + dkbase] = pk;
        }
    } else {
        #pragma unroll
        for (int i = 0; i < 8; ++i) {
            bf16x8 pk;
            #pragma unroll
            for (int j = 0; j < 8; ++j) pk[j] = (__bf16)acc[i][j];
            *(bf16x8*)&Vb[((size_t)(b * NH + h) * DK + dkbase + i) * L_DIM + l0 + col * 8] = pk;
        }
    }
}

// ---------------------------------------------------------------------------
// Kernel 2: flash attention on 32x32x16 MFMAs, no P LDS round-trip.
//   S^T = K·Q^T: D-layout lane col = q = lane&31 matches PV B-operand n-index,
//   so P goes D-regs -> exp -> bf16 pack -> B-frag directly. The kpos reg-order
//   permutation (kpos = (j&3)+4h+8(j>>2) at slot 8h+j) is absorbed into the
//   Vs staging column order, so the A-side (V) sees the SAME permuted kpos.
//   Row sums via ones-A MFMA: lacc[0] = sum_kpos P[kpos][q] per lane, no shuffle.
// Wave = 32 q rows; block = 128 q.
// ---------------------------------------------------------------------------
__global__ __launch_bounds__(256) void attn_kernel(
    const __bf16* __restrict__ Q, const __bf16* __restrict__ K,
    const __bf16* __restrict__ V, __bf16* __restrict__ Att)
{
    const int tid  = threadIdx.x;
    const int wave = tid >> 6;
    const int lane = tid & 63;
    const int n32  = lane & 31;   // q (and d, kpos-row) index
    const int hl   = lane >> 5;   // lane half
    const int h    = blockIdx.y;
    const int b    = blockIdx.z;
    const int bh   = b * NH + h;
    const int q0   = blockIdx.x * 128 + wave * 32;

    __shared__ __attribute__((aligned(16))) __bf16 Ks[64][40];  // [kpos][dk]
    __shared__ __attribute__((aligned(16))) __bf16 Vs[32][72];  // [d][kpos-permuted]

    // Q B-frags: B[k=dk][n=q], lane n=n32, slot j -> dk = ks*16 + hl*8 + j
    bf16x8 qf[2];
    qf[0] = *(const bf16x8*)(Q + ((size_t)bh * L_DIM + q0 + n32) * DK + hl * 8);
    qf[1] = *(const bf16x8*)(Q + ((size_t)bh * L_DIM + q0 + n32) * DK + 16 + hl * 8);

    f32x16 oacc, lacc;
    #pragma unroll
    for (int r = 0; r < 16; ++r) { oacc[r] = 0.f; lacc[r] = 0.f; }

    bf16x8 ones;
    #pragma unroll
    for (int j = 0; j < 8; ++j) ones[j] = (__bf16)1.0f;

    // global staging pointers (b128 per thread per tile)
    const __bf16* kg = K + (size_t)bh * L_DIM * DK + (tid >> 2) * DK + (tid & 3) * 8;
    const __bf16* vg = V + ((size_t)bh * DK + (tid >> 3)) * L_DIM + (tid & 7) * 8;
    __bf16* ksd = &Ks[tid >> 2][(tid & 3) * 8];
    // Vs permuted-column write: 8 contiguous kpos (8a..8a+7) -> cols
    // g*16 + (a&1)*4 (+0..3) and g*16 + 8 + (a&1)*4 (+0..3), g = a>>1
    const int va  = tid & 7;
    __bf16* vsd0 = &Vs[tid >> 3][(va >> 1) * 16 + (va & 1) * 4];
    __bf16* vsd1 = vsd0 + 8;

    bf16x8 kreg = *(const bf16x8*)kg;
    bf16x8 vreg = *(const bf16x8*)vg;

    for (int kt = 0; kt < L_DIM / 64; ++kt) {
        __syncthreads();
        *(bf16x8*)ksd = kreg;
        union { bf16x8 v; uint2 u2[2]; } vv; vv.v = vreg;
        *(uint2*)vsd0 = vv.u2[0];
        *(uint2*)vsd1 = vv.u2[1];
        if (kt < L_DIM / 64 - 1) {
            kreg = *(const bf16x8*)(kg + (size_t)(kt + 1) * 64 * DK);
            vreg = *(const bf16x8*)(vg + (kt + 1) * 64);
        }
        __syncthreads();

        // K A-frags: A[m=kpos][k=dk], lane m = n32 (+32 for mt=1)
        bf16x8 kf0a = *(const bf16x8*)&Ks[n32     ][hl * 8];
        bf16x8 kf0b = *(const bf16x8*)&Ks[n32     ][16 + hl * 8];
        bf16x8 kf1a = *(const bf16x8*)&Ks[32 + n32][hl * 8];
        bf16x8 kf1b = *(const bf16x8*)&Ks[32 + n32][16 + hl * 8];
        // V A-frags: A[m=d][k-slot] over permuted kpos columns
        bf16x8 vf0 = *(const bf16x8*)&Vs[n32][     hl * 8];
        bf16x8 vf1 = *(const bf16x8*)&Vs[n32][16 + hl * 8];
        bf16x8 vf2 = *(const bf16x8*)&Vs[n32][32 + hl * 8];
        bf16x8 vf3 = *(const bf16x8*)&Vs[n32][48 + hl * 8];

        #pragma unroll
        for (int mt = 0; mt < 2; ++mt) {
            f32x16 sz;
            #pragma unroll
            for (int r = 0; r < 16; ++r) sz[r] = 0.f;
            f32x16 s = __builtin_amdgcn_mfma_f32_32x32x16_bf16(
                mt ? kf1a : kf0a, qf[0], sz, 0, 0, 0);
            s = __builtin_amdgcn_mfma_f32_32x32x16_bf16(
                mt ? kf1b : kf0b, qf[1], s, 0, 0, 0);

            // exp2 + pack: pb0 regs hold kpos group mt*32+0..15 (slot order),
            // pb1 -> mt*32+16..31; matches Vs column permutation.
            float e[16];
            #pragma unroll
            for (int r = 0; r < 16; ++r) e[r] = __builtin_amdgcn_exp2f(s[r]);
            union { unsigned u[4]; bf16x8 v; } p0, p1;
            #pragma unroll
            for (int i = 0; i < 4; ++i) {
                p0.u[i] = pk_bf16(e[2 * i],     e[2 * i + 1]);
                p1.u[i] = pk_bf16(e[8 + 2 * i], e[8 + 2 * i + 1]);
            }

            oacc = __builtin_amdgcn_mfma_f32_32x32x16_bf16(
                mt ? vf2 : vf0, p0.v, oacc, 0, 0, 0);
            lacc = __builtin_amdgcn_mfma_f32_32x32x16_bf16(ones, p0.v, lacc, 0, 0, 0);
            oacc = __builtin_amdgcn_mfma_f32_32x32x16_bf16(
                mt ? vf3 : vf1, p1.v, oacc, 0, 0, 0);
            lacc = __builtin_amdgcn_mfma_f32_32x32x16_bf16(ones, p1.v, lacc, 0, 0, 0);
        }
    }

    // epilogue: lacc[0] = lsum for q = n32 (all rows of ones-MFMA identical)
    const float inv = __builtin_amdgcn_rcpf(lacc[0]);
    #pragma unroll
    for (int r = 0; r < 16; ++r) {
        const int d  = (r & 3) + 4 * hl + 8 * (r >> 2);
        float v = oacc[r] * inv;
        v = v > 0.f ? v : 0.f;
        Att[((size_t)b * C_DIM + h * 32 + d) * L_DIM + q0 + n32] = (__bf16)v;
    }
}

// ---------------------------------------------------------------------------
// Kernel 3: final projection, 128o x 64l tiles (512 blocks -> 2 waves/SIMD).
// ---------------------------------------------------------------------------
__global__ __launch_bounds__(256) void final_proj_kernel(
    const __bf16* __restrict__ att, const float* __restrict__ Wl,
    float* __restrict__ y)
{
    const int t   = threadIdx.x;
    const int col = t & 15;      // 16 x 4l
    const int row = t >> 4;      // 16 x 8o
    const int l0  = blockIdx.x * 64;
    const int ob  = blockIdx.y;
    const int b   = blockIdx.z;

    __shared__ __attribute__((aligned(16))) float Ws[32][132];
    __shared__ __attribute__((aligned(16))) float Xs[32][68];

    const int xc = t >> 3, xl = (t & 7) * 8;   // 32c x 64l, 8 f32/thread
    const int wo = t >> 1, wc = (t & 1) * 16;
    const __bf16* ag = att + (size_t)b * C_DIM * L_DIM + (size_t)xc * L_DIM + l0 + xl;
    const float*  wg = Wl + (size_t)(ob * 128 + wo) * C_DIM + wc;

    float acc[8][4];
    #pragma unroll
    for (int i = 0; i < 8; ++i)
        #pragma unroll
        for (int j = 0; j < 4; ++j) acc[i][j] = 0.f;

    bf16x8 ar = *(const bf16x8*)ag;
    f32x4  wr[4];
    #pragma unroll
    for (int k = 0; k < 4; ++k) wr[k] = *(const f32x4*)(wg + k * 4);

    for (int ch = 0; ch < 8; ++ch) {
        __syncthreads();
        {
            f32x4 lo, hi;
            #pragma unroll
            for (int u = 0; u < 4; ++u) { lo[u] = (float)ar[u]; hi[u] = (float)ar[u + 4]; }
            *(f32x4*)&Xs[xc][xl]     = lo;
            *(f32x4*)&Xs[xc][xl + 4] = hi;
        }
        #pragma unroll
        for (int k = 0; k < 4; ++k)
            #pragma unroll
            for (int u = 0; u < 4; ++u)
                Ws[wc + k * 4 + u][wo] = wr[k][u];
        if (ch < 7) {
            ar = *(const bf16x8*)(ag + (size_t)(ch + 1) * 32 * L_DIM);
            #pragma unroll
            for (int k = 0; k < 4; ++k)
                wr[k] = *(const f32x4*)(wg + (ch + 1) * 32 + k * 4);
        }
        __syncthreads();

        #pragma unroll 4
        for (int c = 0; c < 32; ++c) {
            const f32x4 w0 = *(const f32x4*)&Ws[c][row * 8];
            const f32x4 w1 = *(const f32x4*)&Ws[c][row * 8 + 4];
            const f32x4 x0 = *(const f32x4*)&Xs[c][col * 4];
            #pragma unroll
            for (int i = 0; i < 4; ++i)
                #pragma unroll
                for (int j = 0; j < 4; ++j) {
                    acc[i][j]     += w0[i] * x0[j];
                    acc[i + 4][j] += w1[i] * x0[j];
                }
        }
    }

    #pragma unroll
    for (int i = 0; i < 8; ++i) {
        const int o = ob * 128 + row * 8 + i;
        f32x4 v;
        #pragma unroll
        for (int j = 0; j < 4; ++j) v[j] = acc[i][j];
        *(f32x4*)(y + ((size_t)b * C_DIM + o) * L_DIM + l0 + col * 4) = v;
    }
}

// ---------------------------------------------------------------------------
extern "C" void kernel_launch(void* const* d_in, const int* in_sizes, int n_in,
                              void* d_out, int out_size, void* d_ws, size_t ws_size,
                              hipStream_t stream)
{
    const float* x  = (const float*)d_in[0];
    const float* Wq = (const float*)d_in[1];
    const float* Wk = (const float*)d_in[2];
    const float* Wv = (const float*)d_in[3];
    const float* Wl = (const float*)d_in[4];
    float* y = (float*)d_out;

    const size_t n = (size_t)B_DIM * NH * L_DIM * DK;   // 4,194,304 elems
    __bf16* Qb = (__bf16*)d_ws;
    __bf16* Kb = Qb + n;
    __bf16* Vb = Kb + n;
    __bf16* Ab = Vb + n;   // att [B,C,L]

    proj_qkv_kernel<<<dim3(L_DIM/128, 6, B_DIM), 256, 0, stream>>>(
        x, Wq, Wk, Wv, Qb, Kb, Vb);
    attn_kernel<<<dim3(L_DIM/128, NH, B_DIM), 256, 0, stream>>>(Qb, Kb, Vb, Ab);
    final_proj_kernel<<<dim3(L_DIM/64, 2, B_DIM), 256, 0, stream>>>(Ab, Wl, y);
}

// Round 5
// 286.303 us; speedup vs baseline: 1.0526x; 1.0526x over previous
//
#include <hip/hip_runtime.h>

#define L_DIM 4096
#define C_DIM 256
#define B_DIM 4
#define NH 8
#define DK 32

// Folds softmax 1/sqrt(DK) AND log2(e) into Q at projection time, so the
// attention kernel uses a single v_exp_f32 (exp2) per score.
#define QSCALE 0.25507694f   // (1/sqrt(32)) * log2(e)

typedef __bf16 bf16x8 __attribute__((ext_vector_type(8)));
typedef float  f32x4  __attribute__((ext_vector_type(4)));
typedef float  f32x16 __attribute__((ext_vector_type(16)));

// pack two f32 -> packed bf16 pair (round-to-nearest via +0x8000, then byte-perm)
// safe here: inputs are exp() outputs (positive, finite, not near overflow)
static __device__ __forceinline__ unsigned pk_bf16(float lo, float hi) {
    unsigned a = __builtin_bit_cast(unsigned, lo) + 0x8000u;
    unsigned b = __builtin_bit_cast(unsigned, hi) + 0x8000u;
    return __builtin_amdgcn_perm(b, a, 0x07060302u);   // {b[31:16], a[31:16]}
}

// ---------------------------------------------------------------------------
// Kernel 1: Q/K/V projections as register-blocked fp32 GEMM (unchanged).
// ---------------------------------------------------------------------------
__global__ __launch_bounds__(256) void proj_qkv_kernel(
    const float* __restrict__ x, const float* __restrict__ Wq,
    const float* __restrict__ Wk, const float* __restrict__ Wv,
    __bf16* __restrict__ Qb, __bf16* __restrict__ Kb, __bf16* __restrict__ Vb)
{
    const int t   = threadIdx.x;
    const int col = t & 15;
    const int row = t >> 4;
    const int l0  = blockIdx.x * 128;
    const int ob  = blockIdx.y & 1;
    const int p   = blockIdx.y >> 1;
    const int b   = blockIdx.z;
    const float* W = (p == 0) ? Wq : ((p == 1) ? Wk : Wv);

    __shared__ __attribute__((aligned(16))) float Ws[32][132];
    __shared__ __attribute__((aligned(16))) float Xs[32][132];

    const int xc = t >> 3, xl = (t & 7) * 16;
    const int wo = t >> 1, wc = (t & 1) * 16;
    const float* xg = x + (size_t)b * C_DIM * L_DIM + (size_t)xc * L_DIM + l0 + xl;
    const float* wg = W + (size_t)(ob * 128 + wo) * C_DIM + wc;

    float acc[8][8];
    #pragma unroll
    for (int i = 0; i < 8; ++i)
        #pragma unroll
        for (int j = 0; j < 8; ++j) acc[i][j] = 0.f;

    f32x4 xr[4], wr[4];
    #pragma unroll
    for (int k = 0; k < 4; ++k) {
        xr[k] = *(const f32x4*)(xg + k * 4);
        wr[k] = *(const f32x4*)(wg + k * 4);
    }

    for (int ch = 0; ch < 8; ++ch) {
        __syncthreads();
        #pragma unroll
        for (int k = 0; k < 4; ++k) {
            *(f32x4*)&Xs[xc][xl + k * 4] = xr[k];
            #pragma unroll
            for (int u = 0; u < 4; ++u)
                Ws[wc + k * 4 + u][wo] = wr[k][u];
        }
        if (ch < 7) {
            #pragma unroll
            for (int k = 0; k < 4; ++k) {
                xr[k] = *(const f32x4*)(xg + (size_t)(ch + 1) * 32 * L_DIM + k * 4);
                wr[k] = *(const f32x4*)(wg + (ch + 1) * 32 + k * 4);
            }
        }
        __syncthreads();

        #pragma unroll 4
        for (int c = 0; c < 32; ++c) {
            const f32x4 w0 = *(const f32x4*)&Ws[c][row * 8];
            const f32x4 w1 = *(const f32x4*)&Ws[c][row * 8 + 4];
            const f32x4 x0 = *(const f32x4*)&Xs[c][col * 8];
            const f32x4 x1 = *(const f32x4*)&Xs[c][col * 8 + 4];
            #pragma unroll
            for (int i = 0; i < 4; ++i)
                #pragma unroll
                for (int j = 0; j < 4; ++j) {
                    acc[i][j]         += w0[i] * x0[j];
                    acc[i][j + 4]     += w0[i] * x1[j];
                    acc[i + 4][j]     += w1[i] * x0[j];
                    acc[i + 4][j + 4] += w1[i] * x1[j];
                }
        }
    }

    const int h      = ob * 4 + (row >> 2);
    const int dkbase = (row & 3) * 8;

    if (p < 2) {
        __bf16* out = (p == 0) ? Qb : Kb;
        const float sc = (p == 0) ? QSCALE : 1.0f;
        #pragma unroll
        for (int j = 0; j < 8; ++j) {
            const int l = l0 + col * 8 + j;
            bf16x8 pk;
            #pragma unroll
            for (int i = 0; i < 8; ++i) pk[i] = (__bf16)(acc[i][j] * sc);
            *(bf16x8*)&out[((size_t)(b * NH + h) * L_DIM + l) * DK + dkbase] = pk;
        }
    } else {
        #pragma unroll
        for (int i = 0; i < 8; ++i) {
            bf16x8 pk;
            #pragma unroll
            for (int j = 0; j < 8; ++j) pk[j] = (__bf16)acc[i][j];
            *(bf16x8*)&Vb[((size_t)(b * NH + h) * DK + dkbase + i) * L_DIM + l0 + col * 8] = pk;
        }
    }
}

// ---------------------------------------------------------------------------
// Kernel 2: flash attention on 32x32x16 MFMAs, no P LDS round-trip,
// TWO independent q-tiles per wave (64 q rows) for ILP: the S->exp->pack->PV
// chains of qt=0/1 interleave, hiding MFMA + transcendental latency that
// round-4's single-chain version exposed (latency-bound at 2 waves/SIMD).
// kf/vf LDS fragments are reused across both q-tiles (DS per score halved).
// ---------------------------------------------------------------------------
__global__ __launch_bounds__(256) void attn_kernel(
    const __bf16* __restrict__ Q, const __bf16* __restrict__ K,
    const __bf16* __restrict__ V, __bf16* __restrict__ Att)
{
    const int tid  = threadIdx.x;
    const int wave = tid >> 6;
    const int lane = tid & 63;
    const int n32  = lane & 31;   // q (and d, kpos-row) index
    const int hl   = lane >> 5;   // lane half
    const int h    = blockIdx.y;
    const int b    = blockIdx.z;
    const int bh   = b * NH + h;
    const int q0   = blockIdx.x * 256 + wave * 64;   // this wave: 64 q rows

    __shared__ __attribute__((aligned(16))) __bf16 Ks[64][40];  // [kpos][dk]
    __shared__ __attribute__((aligned(16))) __bf16 Vs[32][72];  // [d][kpos-permuted]

    // Q B-frags: B[k=dk][n=q], lane n=n32, slot j -> dk = ks*16 + hl*8 + j
    bf16x8 qf[2][2];
    #pragma unroll
    for (int qt = 0; qt < 2; ++qt) {
        const __bf16* qp = Q + ((size_t)bh * L_DIM + q0 + qt * 32 + n32) * DK;
        qf[qt][0] = *(const bf16x8*)(qp + hl * 8);
        qf[qt][1] = *(const bf16x8*)(qp + 16 + hl * 8);
    }

    f32x16 oacc[2], lacc[2];
    #pragma unroll
    for (int qt = 0; qt < 2; ++qt)
        #pragma unroll
        for (int r = 0; r < 16; ++r) { oacc[qt][r] = 0.f; lacc[qt][r] = 0.f; }

    const f32x16 z16 = {};   // zero C operand (no per-iter re-zeroing)

    bf16x8 ones;
    #pragma unroll
    for (int j = 0; j < 8; ++j) ones[j] = (__bf16)1.0f;

    // global staging pointers (b128 per thread per tile)
    const __bf16* kg = K + (size_t)bh * L_DIM * DK + (tid >> 2) * DK + (tid & 3) * 8;
    const __bf16* vg = V + ((size_t)bh * DK + (tid >> 3)) * L_DIM + (tid & 7) * 8;
    __bf16* ksd = &Ks[tid >> 2][(tid & 3) * 8];
    // Vs permuted-column write: 8 contiguous kpos (8a..8a+7) -> cols
    // g*16 + (a&1)*4 (+0..3) and g*16 + 8 + (a&1)*4 (+0..3), g = a>>1
    const int va  = tid & 7;
    __bf16* vsd0 = &Vs[tid >> 3][(va >> 1) * 16 + (va & 1) * 4];
    __bf16* vsd1 = vsd0 + 8;

    bf16x8 kreg = *(const bf16x8*)kg;
    bf16x8 vreg = *(const bf16x8*)vg;

    for (int kt = 0; kt < L_DIM / 64; ++kt) {
        __syncthreads();
        *(bf16x8*)ksd = kreg;
        union { bf16x8 v; uint2 u2[2]; } vv; vv.v = vreg;
        *(uint2*)vsd0 = vv.u2[0];
        *(uint2*)vsd1 = vv.u2[1];
        {   // branchless prefetch (wraps to tile 0 on the last iter, discarded)
            const int nkt = (kt + 1) & (L_DIM / 64 - 1);
            kreg = *(const bf16x8*)(kg + (size_t)nkt * 64 * DK);
            vreg = *(const bf16x8*)(vg + nkt * 64);
        }
        __syncthreads();

        // K A-frags: A[m=kpos][k=dk], lane m = n32 (+32 for mt=1)
        bf16x8 kf[2][2];
        kf[0][0] = *(const bf16x8*)&Ks[n32     ][hl * 8];
        kf[0][1] = *(const bf16x8*)&Ks[n32     ][16 + hl * 8];
        kf[1][0] = *(const bf16x8*)&Ks[32 + n32][hl * 8];
        kf[1][1] = *(const bf16x8*)&Ks[32 + n32][16 + hl * 8];
        // V A-frags: A[m=d][k-slot] over permuted kpos columns
        bf16x8 vf[4];
        vf[0] = *(const bf16x8*)&Vs[n32][     hl * 8];
        vf[1] = *(const bf16x8*)&Vs[n32][16 + hl * 8];
        vf[2] = *(const bf16x8*)&Vs[n32][32 + hl * 8];
        vf[3] = *(const bf16x8*)&Vs[n32][48 + hl * 8];

        #pragma unroll
        for (int mt = 0; mt < 2; ++mt) {
            // two independent chains (qt=0,1) — scheduler interleaves them
            #pragma unroll
            for (int qt = 0; qt < 2; ++qt) {
                f32x16 s = __builtin_amdgcn_mfma_f32_32x32x16_bf16(
                    kf[mt][0], qf[qt][0], z16, 0, 0, 0);
                s = __builtin_amdgcn_mfma_f32_32x32x16_bf16(
                    kf[mt][1], qf[qt][1], s, 0, 0, 0);

                float e[16];
                #pragma unroll
                for (int r = 0; r < 16; ++r) e[r] = __builtin_amdgcn_exp2f(s[r]);
                union { unsigned u[4]; bf16x8 v; } p0, p1;
                #pragma unroll
                for (int i = 0; i < 4; ++i) {
                    p0.u[i] = pk_bf16(e[2 * i],     e[2 * i + 1]);
                    p1.u[i] = pk_bf16(e[8 + 2 * i], e[8 + 2 * i + 1]);
                }

                oacc[qt] = __builtin_amdgcn_mfma_f32_32x32x16_bf16(
                    vf[mt * 2],     p0.v, oacc[qt], 0, 0, 0);
                lacc[qt] = __builtin_amdgcn_mfma_f32_32x32x16_bf16(
                    ones,           p0.v, lacc[qt], 0, 0, 0);
                oacc[qt] = __builtin_amdgcn_mfma_f32_32x32x16_bf16(
                    vf[mt * 2 + 1], p1.v, oacc[qt], 0, 0, 0);
                lacc[qt] = __builtin_amdgcn_mfma_f32_32x32x16_bf16(
                    ones,           p1.v, lacc[qt], 0, 0, 0);
            }
        }
    }

    // epilogue: lacc[qt][0] = lsum for q = q0+qt*32+n32
    #pragma unroll
    for (int qt = 0; qt < 2; ++qt) {
        const float inv = __builtin_amdgcn_rcpf(lacc[qt][0]);
        #pragma unroll
        for (int r = 0; r < 16; ++r) {
            const int d  = (r & 3) + 4 * hl + 8 * (r >> 2);
            float v = oacc[qt][r] * inv;
            v = v > 0.f ? v : 0.f;
            Att[((size_t)b * C_DIM + h * 32 + d) * L_DIM + q0 + qt * 32 + n32] = (__bf16)v;
        }
    }
}

// ---------------------------------------------------------------------------
// Kernel 3: final projection, 128o x 64l tiles (512 blocks -> 2 waves/SIMD).
// ---------------------------------------------------------------------------
__global__ __launch_bounds__(256) void final_proj_kernel(
    const __bf16* __restrict__ att, const float* __restrict__ Wl,
    float* __restrict__ y)
{
    const int t   = threadIdx.x;
    const int col = t & 15;      // 16 x 4l
    const int row = t >> 4;      // 16 x 8o
    const int l0  = blockIdx.x * 64;
    const int ob  = blockIdx.y;
    const int b   = blockIdx.z;

    __shared__ __attribute__((aligned(16))) float Ws[32][132];
    __shared__ __attribute__((aligned(16))) float Xs[32][68];

    const int xc = t >> 3, xl = (t & 7) * 8;   // 32c x 64l, 8 f32/thread
    const int wo = t >> 1, wc = (t & 1) * 16;
    const __bf16* ag = att + (size_t)b * C_DIM * L_DIM + (size_t)xc * L_DIM + l0 + xl;
    const float*  wg = Wl + (size_t)(ob * 128 + wo) * C_DIM + wc;

    float acc[8][4];
    #pragma unroll
    for (int i = 0; i < 8; ++i)
        #pragma unroll
        for (int j = 0; j < 4; ++j) acc[i][j] = 0.f;

    bf16x8 ar = *(const bf16x8*)ag;
    f32x4  wr[4];
    #pragma unroll
    for (int k = 0; k < 4; ++k) wr[k] = *(const f32x4*)(wg + k * 4);

    for (int ch = 0; ch < 8; ++ch) {
        __syncthreads();
        {
            f32x4 lo, hi;
            #pragma unroll
            for (int u = 0; u < 4; ++u) { lo[u] = (float)ar[u]; hi[u] = (float)ar[u + 4]; }
            *(f32x4*)&Xs[xc][xl]     = lo;
            *(f32x4*)&Xs[xc][xl + 4] = hi;
        }
        #pragma unroll
        for (int k = 0; k < 4; ++k)
            #pragma unroll
            for (int u = 0; u < 4; ++u)
                Ws[wc + k * 4 + u][wo] = wr[k][u];
        if (ch < 7) {
            ar = *(const bf16x8*)(ag + (size_t)(ch + 1) * 32 * L_DIM);
            #pragma unroll
            for (int k = 0; k < 4; ++k)
                wr[k] = *(const f32x4*)(wg + (ch + 1) * 32 + k * 4);
        }
        __syncthreads();

        #pragma unroll 4
        for (int c = 0; c < 32; ++c) {
            const f32x4 w0 = *(const f32x4*)&Ws[c][row * 8];
            const f32x4 w1 = *(const f32x4*)&Ws[c][row * 8 + 4];
            const f32x4 x0 = *(const f32x4*)&Xs[c][col * 4];
            #pragma unroll
            for (int i = 0; i < 4; ++i)
                #pragma unroll
                for (int j = 0; j < 4; ++j) {
                    acc[i][j]     += w0[i] * x0[j];
                    acc[i + 4][j] += w1[i] * x0[j];
                }
        }
    }

    #pragma unroll
    for (int i = 0; i < 8; ++i) {
        const int o = ob * 128 + row * 8 + i;
        f32x4 v;
        #pragma unroll
        for (int j = 0; j < 4; ++j) v[j] = acc[i][j];
        *(f32x4*)(y + ((size_t)b * C_DIM + o) * L_DIM + l0 + col * 4) = v;
    }
}

// ---------------------------------------------------------------------------
extern "C" void kernel_launch(void* const* d_in, const int* in_sizes, int n_in,
                              void* d_out, int out_size, void* d_ws, size_t ws_size,
                              hipStream_t stream)
{
    const float* x  = (const float*)d_in[0];
    const float* Wq = (const float*)d_in[1];
    const float* Wk = (const float*)d_in[2];
    const float* Wv = (const float*)d_in[3];
    const float* Wl = (const float*)d_in[4];
    float* y = (float*)d_out;

    const size_t n = (size_t)B_DIM * NH * L_DIM * DK;   // 4,194,304 elems
    __bf16* Qb = (__bf16*)d_ws;
    __bf16* Kb = Qb + n;
    __bf16* Vb = Kb + n;
    __bf16* Ab = Vb + n;   // att [B,C,L]

    proj_qkv_kernel<<<dim3(L_DIM/128, 6, B_DIM), 256, 0, stream>>>(
        x, Wq, Wk, Wv, Qb, Kb, Vb);
    attn_kernel<<<dim3(L_DIM/256, NH, B_DIM), 256, 0, stream>>>(Qb, Kb, Vb, Ab);
    final_proj_kernel<<<dim3(L_DIM/64, 2, B_DIM), 256, 0, stream>>>(Ab, Wl, y);
}

// Round 6
// 219.952 us; speedup vs baseline: 1.3701x; 1.3017x over previous
//
#include <hip/hip_runtime.h>

#define L_DIM 4096
#define C_DIM 256
#define B_DIM 4
#define NH 8
#define DK 32

// Folds softmax 1/sqrt(DK) AND log2(e) into Wq at staging time, so the
// attention kernel uses a single v_exp_f32 (exp2) per score.
#define QSCALE 0.25507694f   // (1/sqrt(32)) * log2(e)

typedef __bf16 bf16x8 __attribute__((ext_vector_type(8)));
typedef float  f32x4  __attribute__((ext_vector_type(4)));
typedef float  f32x16 __attribute__((ext_vector_type(16)));

// pack two f32 -> packed bf16 pair (round-to-nearest-half-away via +0x8000,
// then byte-perm). Valid for any finite sign-magnitude value (carry stays in
// exp+mantissa); error <= 0.5 ulp_bf16.
static __device__ __forceinline__ unsigned pk_bf16(float lo, float hi) {
    unsigned a = __builtin_bit_cast(unsigned, lo) + 0x8000u;
    unsigned b = __builtin_bit_cast(unsigned, hi) + 0x8000u;
    return __builtin_amdgcn_perm(b, a, 0x07060302u);   // {b[31:16], a[31:16]}
}

// ---------------------------------------------------------------------------
// Kernel 0: x [B,C,L] fp32 -> xt [B,L,C] bf16 (tiled transpose through LDS).
// ---------------------------------------------------------------------------
__global__ __launch_bounds__(256) void transpose_x_kernel(
    const float* __restrict__ x, __bf16* __restrict__ xt)
{
    const int t  = threadIdx.x;
    const int l0 = blockIdx.x * 64;
    const int c0 = blockIdx.y * 64;
    const int b  = blockIdx.z;

    __shared__ __attribute__((aligned(16))) float T[64][65];

    {   // load 64c x 64l tile (coalesced f32x4)
        const int r  = t >> 2;
        const int lc = (t & 3) * 16;
        const float* xp = x + ((size_t)b * C_DIM + c0 + r) * L_DIM + l0 + lc;
        #pragma unroll
        for (int k = 0; k < 4; ++k)
            *(f32x4*)&T[r][lc + k * 4] = *(const f32x4*)(xp + k * 4);
    }
    __syncthreads();
    {   // store transposed+converted (2-way LDS conflicts only -> free)
        const int l  = t >> 2;
        const int cc = (t & 3) * 16;
        unsigned u[8];
        #pragma unroll
        for (int i = 0; i < 8; ++i)
            u[i] = pk_bf16(T[cc + 2 * i][l], T[cc + 2 * i + 1][l]);
        __bf16* op = xt + ((size_t)b * L_DIM + l0 + l) * C_DIM + c0 + cc;
        *(uint4*)op       = make_uint4(u[0], u[1], u[2], u[3]);
        *(uint4*)(op + 8) = make_uint4(u[4], u[5], u[6], u[7]);
    }
}

// ---------------------------------------------------------------------------
// Kernel 1: Q/K/V projections as bf16 MFMA GEMM.
// Block: 128 o x 128 l; 4 waves of 64x64 (2x2 MFMA 32x32x16 tiles).
// K=256 in 4 chunks of 64; W fp32->bf16 converted in staging (QSCALE folded
// for p==0); register prefetch one chunk ahead.
// Q,K out [B,H,L,DK] bf16 ; V out [B,H,DK,L] bf16.
// ---------------------------------------------------------------------------
__global__ __launch_bounds__(256) void proj_mfma_kernel(
    const __bf16* __restrict__ xt, const float* __restrict__ Wq,
    const float* __restrict__ Wk, const float* __restrict__ Wv,
    __bf16* __restrict__ Qb, __bf16* __restrict__ Kb, __bf16* __restrict__ Vb)
{
    const int t    = threadIdx.x;
    const int wave = t >> 6;
    const int lane = t & 63;
    const int n32  = lane & 31;
    const int hl   = lane >> 5;
    const int l0   = blockIdx.x * 128;
    const int ob   = blockIdx.y & 1;
    const int p    = blockIdx.y >> 1;   // 0=Q 1=K 2=V
    const int b    = blockIdx.z;
    const float* W = (p == 0) ? Wq : ((p == 1) ? Wk : Wv);
    const float sc = (p == 0) ? QSCALE : 1.0f;

    __shared__ __attribute__((aligned(16))) __bf16 Wt[128][72];  // [o][c]
    __shared__ __attribute__((aligned(16))) __bf16 Xs[128][72];  // [l][c]

    const int wo  = t >> 1, wcc = (t & 1) * 32;
    const int xl  = t >> 1, xcc = (t & 1) * 32;
    const float*  wg = W + (size_t)(ob * 128 + wo) * C_DIM + wcc;
    const __bf16* xg = xt + ((size_t)b * L_DIM + l0 + xl) * C_DIM + xcc;

    const int moff = (wave & 1) * 64;
    const int noff = (wave >> 1) * 64;

    f32x16 acc[2][2];
    #pragma unroll
    for (int i = 0; i < 2; ++i)
        #pragma unroll
        for (int j = 0; j < 2; ++j)
            #pragma unroll
            for (int r = 0; r < 16; ++r) acc[i][j][r] = 0.f;

    unsigned wpk[16];
    bf16x8   xpr[4];
    #pragma unroll
    for (int k = 0; k < 8; ++k) {
        f32x4 wv = *(const f32x4*)(wg + k * 4);
        wpk[k * 2]     = pk_bf16(wv[0] * sc, wv[1] * sc);
        wpk[k * 2 + 1] = pk_bf16(wv[2] * sc, wv[3] * sc);
    }
    #pragma unroll
    for (int g = 0; g < 4; ++g) xpr[g] = *(const bf16x8*)(xg + g * 8);

    for (int bk = 0; bk < 4; ++bk) {
        __syncthreads();
        #pragma unroll
        for (int g = 0; g < 4; ++g) {
            *(uint4*)&Wt[wo][wcc + g * 8] =
                make_uint4(wpk[g*4], wpk[g*4+1], wpk[g*4+2], wpk[g*4+3]);
            *(bf16x8*)&Xs[xl][xcc + g * 8] = xpr[g];
        }
        if (bk < 3) {
            #pragma unroll
            for (int k = 0; k < 8; ++k) {
                f32x4 wv = *(const f32x4*)(wg + (bk + 1) * 64 + k * 4);
                wpk[k * 2]     = pk_bf16(wv[0] * sc, wv[1] * sc);
                wpk[k * 2 + 1] = pk_bf16(wv[2] * sc, wv[3] * sc);
            }
            #pragma unroll
            for (int g = 0; g < 4; ++g)
                xpr[g] = *(const bf16x8*)(xg + (bk + 1) * 64 + g * 8);
        }
        __syncthreads();

        #pragma unroll
        for (int ks = 0; ks < 4; ++ks) {
            bf16x8 a0 = *(const bf16x8*)&Wt[moff + n32     ][ks * 16 + hl * 8];
            bf16x8 a1 = *(const bf16x8*)&Wt[moff + 32 + n32][ks * 16 + hl * 8];
            bf16x8 b0 = *(const bf16x8*)&Xs[noff + n32     ][ks * 16 + hl * 8];
            bf16x8 b1 = *(const bf16x8*)&Xs[noff + 32 + n32][ks * 16 + hl * 8];
            acc[0][0] = __builtin_amdgcn_mfma_f32_32x32x16_bf16(a0, b0, acc[0][0], 0, 0, 0);
            acc[0][1] = __builtin_amdgcn_mfma_f32_32x32x16_bf16(a0, b1, acc[0][1], 0, 0, 0);
            acc[1][0] = __builtin_amdgcn_mfma_f32_32x32x16_bf16(a1, b0, acc[1][0], 0, 0, 0);
            acc[1][1] = __builtin_amdgcn_mfma_f32_32x32x16_bf16(a1, b1, acc[1][1], 0, 0, 0);
        }
    }

    // epilogue: D[m=o][n=l], o tile == one head's 32 dk exactly
    #pragma unroll
    for (int mt = 0; mt < 2; ++mt) {
        const int o32 = ob * 128 + moff + mt * 32;
        const int h   = o32 >> 5;
        const int bh  = b * NH + h;
        #pragma unroll
        for (int nt = 0; nt < 2; ++nt) {
            const int l = l0 + noff + nt * 32 + n32;
            if (p < 2) {
                __bf16* out = ((p == 0) ? Qb : Kb) + ((size_t)bh * L_DIM + l) * DK;
                #pragma unroll
                for (int g = 0; g < 4; ++g) {
                    unsigned u0 = pk_bf16(acc[mt][nt][g*4],     acc[mt][nt][g*4+1]);
                    unsigned u1 = pk_bf16(acc[mt][nt][g*4+2],   acc[mt][nt][g*4+3]);
                    *(uint2*)(out + 4 * hl + 8 * g) = make_uint2(u0, u1);
                }
            } else {
                #pragma unroll
                for (int r = 0; r < 16; ++r) {
                    const int dk = (r & 3) + 4 * hl + 8 * (r >> 2);
                    Vb[((size_t)bh * DK + dk) * L_DIM + l] = (__bf16)acc[mt][nt][r];
                }
            }
        }
    }
}

// ---------------------------------------------------------------------------
// Kernel 2: flash attention (round-5 structure), epilogue now writes
// att^T [B, L, C] bf16 so the final GEMM can stage it fragment-ready.
// ---------------------------------------------------------------------------
__global__ __launch_bounds__(256) void attn_kernel(
    const __bf16* __restrict__ Q, const __bf16* __restrict__ K,
    const __bf16* __restrict__ V, __bf16* __restrict__ At)
{
    const int tid  = threadIdx.x;
    const int wave = tid >> 6;
    const int lane = tid & 63;
    const int n32  = lane & 31;
    const int hl   = lane >> 5;
    const int h    = blockIdx.y;
    const int b    = blockIdx.z;
    const int bh   = b * NH + h;
    const int q0   = blockIdx.x * 256 + wave * 64;

    __shared__ __attribute__((aligned(16))) __bf16 Ks[64][40];
    __shared__ __attribute__((aligned(16))) __bf16 Vs[32][72];

    bf16x8 qf[2][2];
    #pragma unroll
    for (int qt = 0; qt < 2; ++qt) {
        const __bf16* qp = Q + ((size_t)bh * L_DIM + q0 + qt * 32 + n32) * DK;
        qf[qt][0] = *(const bf16x8*)(qp + hl * 8);
        qf[qt][1] = *(const bf16x8*)(qp + 16 + hl * 8);
    }

    f32x16 oacc[2], lacc[2];
    #pragma unroll
    for (int qt = 0; qt < 2; ++qt)
        #pragma unroll
        for (int r = 0; r < 16; ++r) { oacc[qt][r] = 0.f; lacc[qt][r] = 0.f; }

    const f32x16 z16 = {};

    bf16x8 ones;
    #pragma unroll
    for (int j = 0; j < 8; ++j) ones[j] = (__bf16)1.0f;

    const __bf16* kg = K + (size_t)bh * L_DIM * DK + (tid >> 2) * DK + (tid & 3) * 8;
    const __bf16* vg = V + ((size_t)bh * DK + (tid >> 3)) * L_DIM + (tid & 7) * 8;
    __bf16* ksd = &Ks[tid >> 2][(tid & 3) * 8];
    const int va  = tid & 7;
    __bf16* vsd0 = &Vs[tid >> 3][(va >> 1) * 16 + (va & 1) * 4];
    __bf16* vsd1 = vsd0 + 8;

    bf16x8 kreg = *(const bf16x8*)kg;
    bf16x8 vreg = *(const bf16x8*)vg;

    for (int kt = 0; kt < L_DIM / 64; ++kt) {
        __syncthreads();
        *(bf16x8*)ksd = kreg;
        union { bf16x8 v; uint2 u2[2]; } vv; vv.v = vreg;
        *(uint2*)vsd0 = vv.u2[0];
        *(uint2*)vsd1 = vv.u2[1];
        {
            const int nkt = (kt + 1) & (L_DIM / 64 - 1);
            kreg = *(const bf16x8*)(kg + (size_t)nkt * 64 * DK);
            vreg = *(const bf16x8*)(vg + nkt * 64);
        }
        __syncthreads();

        bf16x8 kf[2][2];
        kf[0][0] = *(const bf16x8*)&Ks[n32     ][hl * 8];
        kf[0][1] = *(const bf16x8*)&Ks[n32     ][16 + hl * 8];
        kf[1][0] = *(const bf16x8*)&Ks[32 + n32][hl * 8];
        kf[1][1] = *(const bf16x8*)&Ks[32 + n32][16 + hl * 8];
        bf16x8 vf[4];
        vf[0] = *(const bf16x8*)&Vs[n32][     hl * 8];
        vf[1] = *(const bf16x8*)&Vs[n32][16 + hl * 8];
        vf[2] = *(const bf16x8*)&Vs[n32][32 + hl * 8];
        vf[3] = *(const bf16x8*)&Vs[n32][48 + hl * 8];

        #pragma unroll
        for (int mt = 0; mt < 2; ++mt) {
            #pragma unroll
            for (int qt = 0; qt < 2; ++qt) {
                f32x16 s = __builtin_amdgcn_mfma_f32_32x32x16_bf16(
                    kf[mt][0], qf[qt][0], z16, 0, 0, 0);
                s = __builtin_amdgcn_mfma_f32_32x32x16_bf16(
                    kf[mt][1], qf[qt][1], s, 0, 0, 0);

                float e[16];
                #pragma unroll
                for (int r = 0; r < 16; ++r) e[r] = __builtin_amdgcn_exp2f(s[r]);
                union { unsigned u[4]; bf16x8 v; } p0, p1;
                #pragma unroll
                for (int i = 0; i < 4; ++i) {
                    p0.u[i] = pk_bf16(e[2 * i],     e[2 * i + 1]);
                    p1.u[i] = pk_bf16(e[8 + 2 * i], e[8 + 2 * i + 1]);
                }

                oacc[qt] = __builtin_amdgcn_mfma_f32_32x32x16_bf16(
                    vf[mt * 2],     p0.v, oacc[qt], 0, 0, 0);
                lacc[qt] = __builtin_amdgcn_mfma_f32_32x32x16_bf16(
                    ones,           p0.v, lacc[qt], 0, 0, 0);
                oacc[qt] = __builtin_amdgcn_mfma_f32_32x32x16_bf16(
                    vf[mt * 2 + 1], p1.v, oacc[qt], 0, 0, 0);
                lacc[qt] = __builtin_amdgcn_mfma_f32_32x32x16_bf16(
                    ones,           p1.v, lacc[qt], 0, 0, 0);
            }
        }
    }

    // epilogue: att^T[b][l][ch], ch = h*32 + d, d = (r&3)+4hl+8(r>>2)
    #pragma unroll
    for (int qt = 0; qt < 2; ++qt) {
        const float inv = __builtin_amdgcn_rcpf(lacc[qt][0]);
        __bf16* ap = At + ((size_t)b * L_DIM + q0 + qt * 32 + n32) * C_DIM
                        + h * 32 + 4 * hl;
        #pragma unroll
        for (int g = 0; g < 4; ++g) {
            float v0 = oacc[qt][g*4]   * inv; v0 = v0 > 0.f ? v0 : 0.f;
            float v1 = oacc[qt][g*4+1] * inv; v1 = v1 > 0.f ? v1 : 0.f;
            float v2 = oacc[qt][g*4+2] * inv; v2 = v2 > 0.f ? v2 : 0.f;
            float v3 = oacc[qt][g*4+3] * inv; v3 = v3 > 0.f ? v3 : 0.f;
            *(uint2*)(ap + 8 * g) = make_uint2(pk_bf16(v0, v1), pk_bf16(v2, v3));
        }
    }
}

// ---------------------------------------------------------------------------
// Kernel 3: final projection as bf16 MFMA GEMM, fp32 output.
// Block: 128 o x 64 l; 4 waves of 64x32 (2 MFMA tiles).
// ---------------------------------------------------------------------------
__global__ __launch_bounds__(256) void final_mfma_kernel(
    const __bf16* __restrict__ at, const float* __restrict__ Wl,
    float* __restrict__ y)
{
    const int t    = threadIdx.x;
    const int wave = t >> 6;
    const int lane = t & 63;
    const int n32  = lane & 31;
    const int hl   = lane >> 5;
    const int l0   = blockIdx.x * 64;
    const int ob   = blockIdx.y;
    const int b    = blockIdx.z;

    __shared__ __attribute__((aligned(16))) __bf16 Wt[128][72];
    __shared__ __attribute__((aligned(16))) __bf16 Xs[64][72];

    const int wo  = t >> 1, wcc = (t & 1) * 32;
    const int xl  = t >> 2, xcc = (t & 3) * 16;
    const float*  wg = Wl + (size_t)(ob * 128 + wo) * C_DIM + wcc;
    const __bf16* xg = at + ((size_t)b * L_DIM + l0 + xl) * C_DIM + xcc;

    const int moff = (wave & 1) * 64;
    const int noff = (wave >> 1) * 32;

    f32x16 acc[2];
    #pragma unroll
    for (int i = 0; i < 2; ++i)
        #pragma unroll
        for (int r = 0; r < 16; ++r) acc[i][r] = 0.f;

    unsigned wpk[16];
    bf16x8   xpr[2];
    #pragma unroll
    for (int k = 0; k < 8; ++k) {
        f32x4 wv = *(const f32x4*)(wg + k * 4);
        wpk[k * 2]     = pk_bf16(wv[0], wv[1]);
        wpk[k * 2 + 1] = pk_bf16(wv[2], wv[3]);
    }
    #pragma unroll
    for (int g = 0; g < 2; ++g) xpr[g] = *(const bf16x8*)(xg + g * 8);

    for (int bk = 0; bk < 4; ++bk) {
        __syncthreads();
        #pragma unroll
        for (int g = 0; g < 4; ++g)
            *(uint4*)&Wt[wo][wcc + g * 8] =
                make_uint4(wpk[g*4], wpk[g*4+1], wpk[g*4+2], wpk[g*4+3]);
        #pragma unroll
        for (int g = 0; g < 2; ++g)
            *(bf16x8*)&Xs[xl][xcc + g * 8] = xpr[g];
        if (bk < 3) {
            #pragma unroll
            for (int k = 0; k < 8; ++k) {
                f32x4 wv = *(const f32x4*)(wg + (bk + 1) * 64 + k * 4);
                wpk[k * 2]     = pk_bf16(wv[0], wv[1]);
                wpk[k * 2 + 1] = pk_bf16(wv[2], wv[3]);
            }
            #pragma unroll
            for (int g = 0; g < 2; ++g)
                xpr[g] = *(const bf16x8*)(xg + (bk + 1) * 64 + g * 8);
        }
        __syncthreads();

        #pragma unroll
        for (int ks = 0; ks < 4; ++ks) {
            bf16x8 a0 = *(const bf16x8*)&Wt[moff + n32     ][ks * 16 + hl * 8];
            bf16x8 a1 = *(const bf16x8*)&Wt[moff + 32 + n32][ks * 16 + hl * 8];
            bf16x8 b0 = *(const bf16x8*)&Xs[noff + n32     ][ks * 16 + hl * 8];
            acc[0] = __builtin_amdgcn_mfma_f32_32x32x16_bf16(a0, b0, acc[0], 0, 0, 0);
            acc[1] = __builtin_amdgcn_mfma_f32_32x32x16_bf16(a1, b0, acc[1], 0, 0, 0);
        }
    }

    #pragma unroll
    for (int mt = 0; mt < 2; ++mt) {
        #pragma unroll
        for (int r = 0; r < 16; ++r) {
            const int o = ob * 128 + moff + mt * 32 + (r & 3) + 4 * hl + 8 * (r >> 2);
            y[((size_t)b * C_DIM + o) * L_DIM + l0 + noff + n32] = acc[mt][r];
        }
    }
}

// ---------------------------------------------------------------------------
extern "C" void kernel_launch(void* const* d_in, const int* in_sizes, int n_in,
                              void* d_out, int out_size, void* d_ws, size_t ws_size,
                              hipStream_t stream)
{
    const float* x  = (const float*)d_in[0];
    const float* Wq = (const float*)d_in[1];
    const float* Wk = (const float*)d_in[2];
    const float* Wv = (const float*)d_in[3];
    const float* Wl = (const float*)d_in[4];
    float* y = (float*)d_out;

    const size_t n = (size_t)B_DIM * NH * L_DIM * DK;   // 4,194,304 elems
    __bf16* Xt = (__bf16*)d_ws;       // [B,L,C]
    __bf16* Qb = Xt + n;              // [B,H,L,DK]
    __bf16* Kb = Qb + n;
    __bf16* Vb = Kb + n;              // [B,H,DK,L]
    __bf16* At = Vb + n;              // att^T [B,L,C]

    transpose_x_kernel<<<dim3(L_DIM/64, C_DIM/64, B_DIM), 256, 0, stream>>>(x, Xt);
    proj_mfma_kernel<<<dim3(L_DIM/128, 6, B_DIM), 256, 0, stream>>>(
        Xt, Wq, Wk, Wv, Qb, Kb, Vb);
    attn_kernel<<<dim3(L_DIM/256, NH, B_DIM), 256, 0, stream>>>(Qb, Kb, Vb, At);
    final_mfma_kernel<<<dim3(L_DIM/64, 2, B_DIM), 256, 0, stream>>>(At, Wl, y);
}

// Round 7
// 216.258 us; speedup vs baseline: 1.3935x; 1.0171x over previous
//
#include <hip/hip_runtime.h>

#define L_DIM 4096
#define C_DIM 256
#define B_DIM 4
#define NH 8
#define DK 32

// Folds softmax 1/sqrt(DK) AND log2(e) into Wq at staging time, so the
// attention kernel uses a single v_exp_f32 (exp2) per score.
#define QSCALE 0.25507694f   // (1/sqrt(32)) * log2(e)

typedef __bf16 bf16x8 __attribute__((ext_vector_type(8)));
typedef float  f32x4  __attribute__((ext_vector_type(4)));
typedef float  f32x16 __attribute__((ext_vector_type(16)));

// pack two f32 -> packed bf16 pair (round-to-nearest via +0x8000, then
// byte-perm). Correct nearest-rounding for finite sign-magnitude values.
static __device__ __forceinline__ unsigned pk_bf16(float lo, float hi) {
    unsigned a = __builtin_bit_cast(unsigned, lo) + 0x8000u;
    unsigned b = __builtin_bit_cast(unsigned, hi) + 0x8000u;
    return __builtin_amdgcn_perm(b, a, 0x07060302u);   // {b[31:16], a[31:16]}
}

// ---------------------------------------------------------------------------
// Kernel 0: x [B,C,L] fp32 -> xt [B,L,C] bf16 (tiled transpose through LDS).
// ---------------------------------------------------------------------------
__global__ __launch_bounds__(256) void transpose_x_kernel(
    const float* __restrict__ x, __bf16* __restrict__ xt)
{
    const int t  = threadIdx.x;
    const int l0 = blockIdx.x * 64;
    const int c0 = blockIdx.y * 64;
    const int b  = blockIdx.z;

    __shared__ __attribute__((aligned(16))) float T[64][65];

    {
        const int r  = t >> 2;
        const int lc = (t & 3) * 16;
        const float* xp = x + ((size_t)b * C_DIM + c0 + r) * L_DIM + l0 + lc;
        #pragma unroll
        for (int k = 0; k < 4; ++k)
            *(f32x4*)&T[r][lc + k * 4] = *(const f32x4*)(xp + k * 4);
    }
    __syncthreads();
    {
        const int l  = t >> 2;
        const int cc = (t & 3) * 16;
        unsigned u[8];
        #pragma unroll
        for (int i = 0; i < 8; ++i)
            u[i] = pk_bf16(T[cc + 2 * i][l], T[cc + 2 * i + 1][l]);
        __bf16* op = xt + ((size_t)b * L_DIM + l0 + l) * C_DIM + c0 + cc;
        *(uint4*)op       = make_uint4(u[0], u[1], u[2], u[3]);
        *(uint4*)(op + 8) = make_uint4(u[4], u[5], u[6], u[7]);
    }
}

// ---------------------------------------------------------------------------
// Kernel 1: Q/K/V projections as bf16 MFMA GEMM (unchanged from round 6).
// ---------------------------------------------------------------------------
__global__ __launch_bounds__(256) void proj_mfma_kernel(
    const __bf16* __restrict__ xt, const float* __restrict__ Wq,
    const float* __restrict__ Wk, const float* __restrict__ Wv,
    __bf16* __restrict__ Qb, __bf16* __restrict__ Kb, __bf16* __restrict__ Vb)
{
    const int t    = threadIdx.x;
    const int wave = t >> 6;
    const int lane = t & 63;
    const int n32  = lane & 31;
    const int hl   = lane >> 5;
    const int l0   = blockIdx.x * 128;
    const int ob   = blockIdx.y & 1;
    const int p    = blockIdx.y >> 1;   // 0=Q 1=K 2=V
    const int b    = blockIdx.z;
    const float* W = (p == 0) ? Wq : ((p == 1) ? Wk : Wv);
    const float sc = (p == 0) ? QSCALE : 1.0f;

    __shared__ __attribute__((aligned(16))) __bf16 Wt[128][72];  // [o][c]
    __shared__ __attribute__((aligned(16))) __bf16 Xs[128][72];  // [l][c]

    const int wo  = t >> 1, wcc = (t & 1) * 32;
    const int xl  = t >> 1, xcc = (t & 1) * 32;
    const float*  wg = W + (size_t)(ob * 128 + wo) * C_DIM + wcc;
    const __bf16* xg = xt + ((size_t)b * L_DIM + l0 + xl) * C_DIM + xcc;

    const int moff = (wave & 1) * 64;
    const int noff = (wave >> 1) * 64;

    f32x16 acc[2][2];
    #pragma unroll
    for (int i = 0; i < 2; ++i)
        #pragma unroll
        for (int j = 0; j < 2; ++j)
            #pragma unroll
            for (int r = 0; r < 16; ++r) acc[i][j][r] = 0.f;

    unsigned wpk[16];
    bf16x8   xpr[4];
    #pragma unroll
    for (int k = 0; k < 8; ++k) {
        f32x4 wv = *(const f32x4*)(wg + k * 4);
        wpk[k * 2]     = pk_bf16(wv[0] * sc, wv[1] * sc);
        wpk[k * 2 + 1] = pk_bf16(wv[2] * sc, wv[3] * sc);
    }
    #pragma unroll
    for (int g = 0; g < 4; ++g) xpr[g] = *(const bf16x8*)(xg + g * 8);

    for (int bk = 0; bk < 4; ++bk) {
        __syncthreads();
        #pragma unroll
        for (int g = 0; g < 4; ++g) {
            *(uint4*)&Wt[wo][wcc + g * 8] =
                make_uint4(wpk[g*4], wpk[g*4+1], wpk[g*4+2], wpk[g*4+3]);
            *(bf16x8*)&Xs[xl][xcc + g * 8] = xpr[g];
        }
        if (bk < 3) {
            #pragma unroll
            for (int k = 0; k < 8; ++k) {
                f32x4 wv = *(const f32x4*)(wg + (bk + 1) * 64 + k * 4);
                wpk[k * 2]     = pk_bf16(wv[0] * sc, wv[1] * sc);
                wpk[k * 2 + 1] = pk_bf16(wv[2] * sc, wv[3] * sc);
            }
            #pragma unroll
            for (int g = 0; g < 4; ++g)
                xpr[g] = *(const bf16x8*)(xg + (bk + 1) * 64 + g * 8);
        }
        __syncthreads();

        #pragma unroll
        for (int ks = 0; ks < 4; ++ks) {
            bf16x8 a0 = *(const bf16x8*)&Wt[moff + n32     ][ks * 16 + hl * 8];
            bf16x8 a1 = *(const bf16x8*)&Wt[moff + 32 + n32][ks * 16 + hl * 8];
            bf16x8 b0 = *(const bf16x8*)&Xs[noff + n32     ][ks * 16 + hl * 8];
            bf16x8 b1 = *(const bf16x8*)&Xs[noff + 32 + n32][ks * 16 + hl * 8];
            acc[0][0] = __builtin_amdgcn_mfma_f32_32x32x16_bf16(a0, b0, acc[0][0], 0, 0, 0);
            acc[0][1] = __builtin_amdgcn_mfma_f32_32x32x16_bf16(a0, b1, acc[0][1], 0, 0, 0);
            acc[1][0] = __builtin_amdgcn_mfma_f32_32x32x16_bf16(a1, b0, acc[1][0], 0, 0, 0);
            acc[1][1] = __builtin_amdgcn_mfma_f32_32x32x16_bf16(a1, b1, acc[1][1], 0, 0, 0);
        }
    }

    #pragma unroll
    for (int mt = 0; mt < 2; ++mt) {
        const int o32 = ob * 128 + moff + mt * 32;
        const int h   = o32 >> 5;
        const int bh  = b * NH + h;
        #pragma unroll
        for (int nt = 0; nt < 2; ++nt) {
            const int l = l0 + noff + nt * 32 + n32;
            if (p < 2) {
                __bf16* out = ((p == 0) ? Qb : Kb) + ((size_t)bh * L_DIM + l) * DK;
                #pragma unroll
                for (int g = 0; g < 4; ++g) {
                    unsigned u0 = pk_bf16(acc[mt][nt][g*4],     acc[mt][nt][g*4+1]);
                    unsigned u1 = pk_bf16(acc[mt][nt][g*4+2],   acc[mt][nt][g*4+3]);
                    *(uint2*)(out + 4 * hl + 8 * g) = make_uint2(u0, u1);
                }
            } else {
                #pragma unroll
                for (int r = 0; r < 16; ++r) {
                    const int dk = (r & 3) + 4 * hl + 8 * (r >> 2);
                    Vb[((size_t)bh * DK + dk) * L_DIM + l] = (__bf16)acc[mt][nt][r];
                }
            }
        }
    }
}

// ---------------------------------------------------------------------------
// Kernel 2: flash attention, K-SPLIT x2: each block handles half the kpos
// range (32 KV tiles), doubling wave count -> 4 waves/SIMD while keeping the
// 4-chain per-wave ILP. Epilogue stores UNNORMALIZED O-half (bf16, [B,L,C]
// layout) + per-row exp-sum (f32). Combine happens in final_mfma staging.
// ---------------------------------------------------------------------------
__global__ __launch_bounds__(256) void attn_kernel(
    const __bf16* __restrict__ Q, const __bf16* __restrict__ K,
    const __bf16* __restrict__ V, __bf16* __restrict__ Op0,
    __bf16* __restrict__ Op1, float* __restrict__ Ls)
{
    const int tid   = threadIdx.x;
    const int wave  = tid >> 6;
    const int lane  = tid & 63;
    const int n32   = lane & 31;
    const int hl    = lane >> 5;
    const int h     = blockIdx.y;
    const int b     = blockIdx.z >> 1;
    const int khalf = blockIdx.z & 1;
    const int bh    = b * NH + h;
    const int q0    = blockIdx.x * 256 + wave * 64;
    const int kt0   = khalf * 32;      // this block's 32 KV tiles

    __shared__ __attribute__((aligned(16))) __bf16 Ks[64][40];
    __shared__ __attribute__((aligned(16))) __bf16 Vs[32][72];

    bf16x8 qf[2][2];
    #pragma unroll
    for (int qt = 0; qt < 2; ++qt) {
        const __bf16* qp = Q + ((size_t)bh * L_DIM + q0 + qt * 32 + n32) * DK;
        qf[qt][0] = *(const bf16x8*)(qp + hl * 8);
        qf[qt][1] = *(const bf16x8*)(qp + 16 + hl * 8);
    }

    f32x16 oacc[2], lacc[2];
    #pragma unroll
    for (int qt = 0; qt < 2; ++qt)
        #pragma unroll
        for (int r = 0; r < 16; ++r) { oacc[qt][r] = 0.f; lacc[qt][r] = 0.f; }

    const f32x16 z16 = {};

    bf16x8 ones;
    #pragma unroll
    for (int j = 0; j < 8; ++j) ones[j] = (__bf16)1.0f;

    const __bf16* kg = K + (size_t)bh * L_DIM * DK + (tid >> 2) * DK + (tid & 3) * 8;
    const __bf16* vg = V + ((size_t)bh * DK + (tid >> 3)) * L_DIM + (tid & 7) * 8;
    __bf16* ksd = &Ks[tid >> 2][(tid & 3) * 8];
    const int va  = tid & 7;
    __bf16* vsd0 = &Vs[tid >> 3][(va >> 1) * 16 + (va & 1) * 4];
    __bf16* vsd1 = vsd0 + 8;

    bf16x8 kreg = *(const bf16x8*)(kg + (size_t)kt0 * 64 * DK);
    bf16x8 vreg = *(const bf16x8*)(vg + kt0 * 64);

    for (int kt = 0; kt < 32; ++kt) {
        __syncthreads();
        *(bf16x8*)ksd = kreg;
        union { bf16x8 v; uint2 u2[2]; } vv; vv.v = vreg;
        *(uint2*)vsd0 = vv.u2[0];
        *(uint2*)vsd1 = vv.u2[1];
        {   // branchless prefetch (wraps within the half, discarded on last)
            const int nkt = kt0 + ((kt + 1) & 31);
            kreg = *(const bf16x8*)(kg + (size_t)nkt * 64 * DK);
            vreg = *(const bf16x8*)(vg + nkt * 64);
        }
        __syncthreads();

        bf16x8 kf[2][2];
        kf[0][0] = *(const bf16x8*)&Ks[n32     ][hl * 8];
        kf[0][1] = *(const bf16x8*)&Ks[n32     ][16 + hl * 8];
        kf[1][0] = *(const bf16x8*)&Ks[32 + n32][hl * 8];
        kf[1][1] = *(const bf16x8*)&Ks[32 + n32][16 + hl * 8];
        bf16x8 vf[4];
        vf[0] = *(const bf16x8*)&Vs[n32][     hl * 8];
        vf[1] = *(const bf16x8*)&Vs[n32][16 + hl * 8];
        vf[2] = *(const bf16x8*)&Vs[n32][32 + hl * 8];
        vf[3] = *(const bf16x8*)&Vs[n32][48 + hl * 8];

        #pragma unroll
        for (int mt = 0; mt < 2; ++mt) {
            #pragma unroll
            for (int qt = 0; qt < 2; ++qt) {
                f32x16 s = __builtin_amdgcn_mfma_f32_32x32x16_bf16(
                    kf[mt][0], qf[qt][0], z16, 0, 0, 0);
                s = __builtin_amdgcn_mfma_f32_32x32x16_bf16(
                    kf[mt][1], qf[qt][1], s, 0, 0, 0);

                float e[16];
                #pragma unroll
                for (int r = 0; r < 16; ++r) e[r] = __builtin_amdgcn_exp2f(s[r]);
                union { unsigned u[4]; bf16x8 v; } p0, p1;
                #pragma unroll
                for (int i = 0; i < 4; ++i) {
                    p0.u[i] = pk_bf16(e[2 * i],     e[2 * i + 1]);
                    p1.u[i] = pk_bf16(e[8 + 2 * i], e[8 + 2 * i + 1]);
                }

                oacc[qt] = __builtin_amdgcn_mfma_f32_32x32x16_bf16(
                    vf[mt * 2],     p0.v, oacc[qt], 0, 0, 0);
                lacc[qt] = __builtin_amdgcn_mfma_f32_32x32x16_bf16(
                    ones,           p0.v, lacc[qt], 0, 0, 0);
                oacc[qt] = __builtin_amdgcn_mfma_f32_32x32x16_bf16(
                    vf[mt * 2 + 1], p1.v, oacc[qt], 0, 0, 0);
                lacc[qt] = __builtin_amdgcn_mfma_f32_32x32x16_bf16(
                    ones,           p1.v, lacc[qt], 0, 0, 0);
            }
        }
    }

    // epilogue: unnormalized O-half -> Op[khalf] in [B,L,C] layout; lsum -> Ls
    __bf16* Op = khalf ? Op1 : Op0;
    #pragma unroll
    for (int qt = 0; qt < 2; ++qt) {
        const int l = q0 + qt * 32 + n32;
        __bf16* ap = Op + ((size_t)b * L_DIM + l) * C_DIM + h * 32 + 4 * hl;
        #pragma unroll
        for (int g = 0; g < 4; ++g) {
            *(uint2*)(ap + 8 * g) = make_uint2(
                pk_bf16(oacc[qt][g*4],     oacc[qt][g*4+1]),
                pk_bf16(oacc[qt][g*4+2],   oacc[qt][g*4+3]));
        }
        Ls[((size_t)khalf * B_DIM * NH + bh) * L_DIM + l] = lacc[qt][0];
    }
}

// ---------------------------------------------------------------------------
// Kernel 3: final projection as bf16 MFMA GEMM with the K-split combine
// fused into staging: at = relu((O1+O2)/(l1+l2)).
// ---------------------------------------------------------------------------
__global__ __launch_bounds__(256) void final_mfma_kernel(
    const __bf16* __restrict__ Op0, const __bf16* __restrict__ Op1,
    const float* __restrict__ Ls, const float* __restrict__ Wl,
    float* __restrict__ y)
{
    const int t    = threadIdx.x;
    const int wave = t >> 6;
    const int lane = t & 63;
    const int n32  = lane & 31;
    const int hl   = lane >> 5;
    const int l0   = blockIdx.x * 64;
    const int ob   = blockIdx.y;
    const int b    = blockIdx.z;

    __shared__ __attribute__((aligned(16))) __bf16 Wt[128][72];
    __shared__ __attribute__((aligned(16))) __bf16 Xs[64][72];

    const int wo  = t >> 1, wcc = (t & 1) * 32;
    const int xl  = t >> 2, xcc = (t & 3) * 16;
    const float* wg = Wl + (size_t)(ob * 128 + wo) * C_DIM + wcc;
    const size_t obase = ((size_t)b * L_DIM + l0 + xl) * C_DIM + xcc;

    // per-bk inverse denominators: head for chunk bk is bk*2 + (xcc>>5 within 64)
    float inv[4];
    {
        const int lidx = l0 + xl;
        #pragma unroll
        for (int bk = 0; bk < 4; ++bk) {
            const int hh = (bk * 64 + xcc) >> 5;
            const float l1 = Ls[((size_t)0 * B_DIM * NH + b * NH + hh) * L_DIM + lidx];
            const float l2 = Ls[((size_t)1 * B_DIM * NH + b * NH + hh) * L_DIM + lidx];
            inv[bk] = __builtin_amdgcn_rcpf(l1 + l2);
        }
    }

    const int moff = (wave & 1) * 64;
    const int noff = (wave >> 1) * 32;

    f32x16 acc[2];
    #pragma unroll
    for (int i = 0; i < 2; ++i)
        #pragma unroll
        for (int r = 0; r < 16; ++r) acc[i][r] = 0.f;

    unsigned wpk[16];
    bf16x8   o1r, o2r;
    #pragma unroll
    for (int k = 0; k < 8; ++k) {
        f32x4 wv = *(const f32x4*)(wg + k * 4);
        wpk[k * 2]     = pk_bf16(wv[0], wv[1]);
        wpk[k * 2 + 1] = pk_bf16(wv[2], wv[3]);
    }
    o1r = *(const bf16x8*)(Op0 + obase);
    o2r = *(const bf16x8*)(Op1 + obase);
    bf16x8 o1r2 = *(const bf16x8*)(Op0 + obase + 8);
    bf16x8 o2r2 = *(const bf16x8*)(Op1 + obase + 8);

    for (int bk = 0; bk < 4; ++bk) {
        __syncthreads();
        #pragma unroll
        for (int g = 0; g < 4; ++g)
            *(uint4*)&Wt[wo][wcc + g * 8] =
                make_uint4(wpk[g*4], wpk[g*4+1], wpk[g*4+2], wpk[g*4+3]);
        {   // combine halves: relu((O1+O2)*inv) -> bf16 fragment row
            unsigned u[4];
            #pragma unroll
            for (int i = 0; i < 4; ++i) {
                float v0 = ((float)o1r[2*i]   + (float)o2r[2*i]  ) * inv[bk];
                float v1 = ((float)o1r[2*i+1] + (float)o2r[2*i+1]) * inv[bk];
                v0 = v0 > 0.f ? v0 : 0.f;
                v1 = v1 > 0.f ? v1 : 0.f;
                u[i] = pk_bf16(v0, v1);
            }
            *(uint4*)&Xs[xl][xcc] = make_uint4(u[0], u[1], u[2], u[3]);
            #pragma unroll
            for (int i = 0; i < 4; ++i) {
                float v0 = ((float)o1r2[2*i]   + (float)o2r2[2*i]  ) * inv[bk];
                float v1 = ((float)o1r2[2*i+1] + (float)o2r2[2*i+1]) * inv[bk];
                v0 = v0 > 0.f ? v0 : 0.f;
                v1 = v1 > 0.f ? v1 : 0.f;
                u[i] = pk_bf16(v0, v1);
            }
            *(uint4*)&Xs[xl][xcc + 8] = make_uint4(u[0], u[1], u[2], u[3]);
        }
        if (bk < 3) {
            #pragma unroll
            for (int k = 0; k < 8; ++k) {
                f32x4 wv = *(const f32x4*)(wg + (bk + 1) * 64 + k * 4);
                wpk[k * 2]     = pk_bf16(wv[0], wv[1]);
                wpk[k * 2 + 1] = pk_bf16(wv[2], wv[3]);
            }
            o1r  = *(const bf16x8*)(Op0 + obase + (bk + 1) * 64);
            o2r  = *(const bf16x8*)(Op1 + obase + (bk + 1) * 64);
            o1r2 = *(const bf16x8*)(Op0 + obase + (bk + 1) * 64 + 8);
            o2r2 = *(const bf16x8*)(Op1 + obase + (bk + 1) * 64 + 8);
        }
        __syncthreads();

        #pragma unroll
        for (int ks = 0; ks < 4; ++ks) {
            bf16x8 a0 = *(const bf16x8*)&Wt[moff + n32     ][ks * 16 + hl * 8];
            bf16x8 a1 = *(const bf16x8*)&Wt[moff + 32 + n32][ks * 16 + hl * 8];
            bf16x8 b0 = *(const bf16x8*)&Xs[noff + n32     ][ks * 16 + hl * 8];
            acc[0] = __builtin_amdgcn_mfma_f32_32x32x16_bf16(a0, b0, acc[0], 0, 0, 0);
            acc[1] = __builtin_amdgcn_mfma_f32_32x32x16_bf16(a1, b0, acc[1], 0, 0, 0);
        }
    }

    #pragma unroll
    for (int mt = 0; mt < 2; ++mt) {
        #pragma unroll
        for (int r = 0; r < 16; ++r) {
            const int o = ob * 128 + moff + mt * 32 + (r & 3) + 4 * hl + 8 * (r >> 2);
            y[((size_t)b * C_DIM + o) * L_DIM + l0 + noff + n32] = acc[mt][r];
        }
    }
}

// ---------------------------------------------------------------------------
extern "C" void kernel_launch(void* const* d_in, const int* in_sizes, int n_in,
                              void* d_out, int out_size, void* d_ws, size_t ws_size,
                              hipStream_t stream)
{
    const float* x  = (const float*)d_in[0];
    const float* Wq = (const float*)d_in[1];
    const float* Wk = (const float*)d_in[2];
    const float* Wv = (const float*)d_in[3];
    const float* Wl = (const float*)d_in[4];
    float* y = (float*)d_out;

    const size_t n = (size_t)B_DIM * NH * L_DIM * DK;   // 4,194,304 elems
    __bf16* Qb  = (__bf16*)d_ws;          // [B,H,L,DK]
    __bf16* Kb  = Qb + n;
    __bf16* Vb  = Kb + n;                 // [B,H,DK,L]
    __bf16* Xt  = Vb + n;                 // [B,L,C]; dead after proj
    __bf16* Op0 = Xt;                     // aliases Xt: O-half 0, [B,L,C]
    __bf16* Op1 = Xt + n;                 // O-half 1
    float*  Ls  = (float*)(Op1 + n);      // [2][B*NH][L] exp-sums

    transpose_x_kernel<<<dim3(L_DIM/64, C_DIM/64, B_DIM), 256, 0, stream>>>(x, Xt);
    proj_mfma_kernel<<<dim3(L_DIM/128, 6, B_DIM), 256, 0, stream>>>(
        Xt, Wq, Wk, Wv, Qb, Kb, Vb);
    attn_kernel<<<dim3(L_DIM/256, NH, B_DIM * 2), 256, 0, stream>>>(
        Qb, Kb, Vb, Op0, Op1, Ls);
    final_mfma_kernel<<<dim3(L_DIM/64, 2, B_DIM), 256, 0, stream>>>(
        Op0, Op1, Ls, Wl, y);
}